// Round 1
// baseline (15850.826 us; speedup 1.0000x reference)
//
#include <hip/hip_runtime.h>
#include <hip/hip_bf16.h>
#include <math.h>

// ---------------- model constants ----------------
constexpr int BATCH = 32;
constexpr int DMODEL = 768;
constexpr int NHEAD = 12;
constexpr int HDIM = 64;
constexpr int DEPTH = 12;
constexpr int L0TOK = 196;           // tokens without cls
constexpr int MAXK = 138;            // largest kept-k
constexpr float ATT_SCALE = 0.125f;  // 64^-0.5

// workspace layout (float offsets)
constexpr size_t SZ_T = (size_t)BATCH * 197 * DMODEL;       // 4,841,472
constexpr size_t SZ_BIG = (size_t)BATCH * 197 * 3072;       // 19,365,888 (>= qkv 14.5M)
constexpr size_t OFF_T0 = 0;
constexpr size_t OFF_T1 = SZ_T;
constexpr size_t OFF_T2 = 2 * SZ_T;
constexpr size_t OFF_GLOB = OFF_T2 + SZ_BIG;
constexpr size_t OFF_SCORE = OFF_GLOB + (size_t)BATCH * 384;
constexpr size_t OFF_KIDX = OFF_SCORE + (size_t)BATCH * L0TOK;
constexpr size_t OFF_CLS = OFF_KIDX + (size_t)BATCH * 140;

__device__ __forceinline__ float gelu_f(float x) {
    return 0.5f * x * (1.0f + erff(x * 0.7071067811865476f));
}

// ---------------- patch rearrange ----------------
__global__ void patch_kernel(const float* __restrict__ x, float* __restrict__ p) {
    int idx = blockIdx.x * 256 + threadIdx.x;             // B*196*768 total
    int c = idx % 768;
    int rest = idx / 768;
    int l = rest % 196;
    int b = rest / 196;
    int ch = c >> 8;                  // /256
    int py = (c & 255) >> 4;
    int px = c & 15;
    int gy = l / 14, gx = l % 14;
    p[idx] = x[(((size_t)b * 3 + ch) * 224 + gy * 16 + py) * 224 + gx * 16 + px];
}

// ---------------- assemble t = [cls; patches] + pos ----------------
__global__ void assemble_kernel(const float* __restrict__ pe, const float* __restrict__ cls,
                                const float* __restrict__ pos, float* __restrict__ t) {
    int row = blockIdx.x;             // b*197 + l
    int b = row / 197, l = row % 197;
    for (int c = threadIdx.x; c < 768; c += 256) {
        float v = (l == 0) ? cls[c] : pe[((size_t)(b * 196 + l - 1)) * 768 + c];
        t[(size_t)row * 768 + c] = v + pos[l * 768 + c];
    }
}

// ---------------- layernorm (flexible row mapping) ----------------
// row index = blockIdx.x -> batch b = row / R, r = row % R
// src row at src + (b*SB + SO + r)*768 ; dst row at dst + (b*DB + DO_ + r)*768
__global__ __launch_bounds__(256)
void ln_kernel(const float* __restrict__ src, float* __restrict__ dst,
               const float* __restrict__ g, const float* __restrict__ bb,
               int R, int SB, int SO, int DB, int DO_) {
    __shared__ float red[256];
    int row = blockIdx.x;
    int b = row / R, r = row % R;
    const float* sp = src + ((size_t)b * SB + SO + r) * 768;
    float* dp = dst + ((size_t)b * DB + DO_ + r) * 768;
    int tid = threadIdx.x;
    float x0 = sp[tid], x1 = sp[tid + 256], x2 = sp[tid + 512];
    red[tid] = x0 + x1 + x2;
    __syncthreads();
    for (int st = 128; st > 0; st >>= 1) {
        if (tid < st) red[tid] += red[tid + st];
        __syncthreads();
    }
    float mean = red[0] * (1.0f / 768.0f);
    __syncthreads();
    float d0 = x0 - mean, d1 = x1 - mean, d2 = x2 - mean;
    red[tid] = d0 * d0 + d1 * d1 + d2 * d2;
    __syncthreads();
    for (int st = 128; st > 0; st >>= 1) {
        if (tid < st) red[tid] += red[tid + st];
        __syncthreads();
    }
    float inv = rsqrtf(red[0] * (1.0f / 768.0f) + 1e-6f);
    dp[tid]       = d0 * inv * g[tid]       + bb[tid];
    dp[tid + 256] = d1 * inv * g[tid + 256] + bb[tid + 256];
    dp[tid + 512] = d2 * inv * g[tid + 512] + bb[tid + 512];
}

// ---------------- generic GEMM: C = A(MxK) @ W(NxK)^T + bias [+gelu | +res] ----------------
// EPI: 0 = bias, 1 = bias+gelu, 2 = bias+residual
template <int EPI>
__global__ __launch_bounds__(256)
void gemm_kernel(const float* __restrict__ A, const float* __restrict__ W,
                 const float* __restrict__ bias, const float* __restrict__ res,
                 float* __restrict__ C, int M, int N, int K) {
    __shared__ float As[16][64];
    __shared__ float Ws[16][64];
    int tid = threadIdx.x;
    int tx = tid & 15, ty = tid >> 4;
    int m0 = blockIdx.y * 64, n0 = blockIdx.x * 64;
    int lr = tid >> 2;          // 0..63
    int lk = (tid & 3) * 4;     // 0,4,8,12
    float acc[4][4] = {};
    for (int kb = 0; kb < K; kb += 16) {
        {
            int m = m0 + lr;
            float4 v = make_float4(0.f, 0.f, 0.f, 0.f);
            if (m < M) v = *(const float4*)(A + (size_t)m * K + kb + lk);
            As[lk + 0][lr] = v.x; As[lk + 1][lr] = v.y;
            As[lk + 2][lr] = v.z; As[lk + 3][lr] = v.w;
            int n = n0 + lr;
            float4 w = make_float4(0.f, 0.f, 0.f, 0.f);
            if (n < N) w = *(const float4*)(W + (size_t)n * K + kb + lk);
            Ws[lk + 0][lr] = w.x; Ws[lk + 1][lr] = w.y;
            Ws[lk + 2][lr] = w.z; Ws[lk + 3][lr] = w.w;
        }
        __syncthreads();
#pragma unroll
        for (int kk = 0; kk < 16; kk++) {
            float a[4], bv[4];
#pragma unroll
            for (int i = 0; i < 4; i++) a[i] = As[kk][ty * 4 + i];
#pragma unroll
            for (int j = 0; j < 4; j++) bv[j] = Ws[kk][tx * 4 + j];
#pragma unroll
            for (int i = 0; i < 4; i++)
#pragma unroll
                for (int j = 0; j < 4; j++) acc[i][j] += a[i] * bv[j];
        }
        __syncthreads();
    }
#pragma unroll
    for (int i = 0; i < 4; i++) {
        int m = m0 + ty * 4 + i;
        if (m >= M) break;
#pragma unroll
        for (int j = 0; j < 4; j++) {
            int n = n0 + tx * 4 + j;
            if (n >= N) continue;
            float v = acc[i][j] + bias[n];
            if (EPI == 1) v = gelu_f(v);
            if (EPI == 2) v += res[(size_t)m * N + n];
            C[(size_t)m * N + n] = v;
        }
    }
}

static inline void gemm(hipStream_t st, const float* A, const float* W, const float* bias,
                        const float* res, float* C, int M, int N, int K, int epi) {
    dim3 g((N + 63) / 64, (M + 63) / 64), b(256);
    if (epi == 0)      gemm_kernel<0><<<g, b, 0, st>>>(A, W, bias, res, C, M, N, K);
    else if (epi == 1) gemm_kernel<1><<<g, b, 0, st>>>(A, W, bias, res, C, M, N, K);
    else               gemm_kernel<2><<<g, b, 0, st>>>(A, W, bias, res, C, M, N, K);
}

// ---------------- attention: one block per (b, h, query) ----------------
__global__ __launch_bounds__(128)
void attn_kernel(const float* __restrict__ qkv, float* __restrict__ o, int L) {
    __shared__ float qs[64];
    __shared__ float ps[224];
    __shared__ float red[128];
    int tid = threadIdx.x;
    int idx = blockIdx.x;
    int qi = idx % L; idx /= L;
    int h = idx % NHEAD;
    int b = idx / NHEAD;
    const float* base = qkv + (size_t)(b * L) * 2304 + h * 64;
    if (tid < 64) qs[tid] = base[(size_t)qi * 2304 + tid];
    __syncthreads();
    for (int j = tid; j < L; j += 128) {
        const float* kr = base + (size_t)j * 2304 + 768;
        float s = 0.f;
#pragma unroll 16
        for (int d = 0; d < 64; d++) s += qs[d] * kr[d];
        ps[j] = s * ATT_SCALE;
    }
    __syncthreads();
    float mx = -1e30f;
    for (int j = tid; j < L; j += 128) mx = fmaxf(mx, ps[j]);
    red[tid] = mx;
    __syncthreads();
    for (int st = 64; st > 0; st >>= 1) {
        if (tid < st) red[tid] = fmaxf(red[tid], red[tid + st]);
        __syncthreads();
    }
    mx = red[0];
    __syncthreads();
    float sm = 0.f;
    for (int j = tid; j < L; j += 128) {
        float e = __expf(ps[j] - mx);
        ps[j] = e;
        sm += e;
    }
    red[tid] = sm;
    __syncthreads();
    for (int st = 64; st > 0; st >>= 1) {
        if (tid < st) red[tid] += red[tid + st];
        __syncthreads();
    }
    float inv = 1.0f / red[0];
    if (tid < 64) {
        int d = tid;
        float acc = 0.f;
        for (int j = 0; j < L; j++) acc += ps[j] * base[(size_t)j * 2304 + 1536 + d];
        o[((size_t)(b * L + qi)) * 768 + h * 64 + d] = acc * inv;
    }
}

// ---------------- predictor helpers ----------------
__global__ void globmean_kernel(const float* __restrict__ hp, float* __restrict__ glob, int Lc) {
    int b = blockIdx.x;
    int c = threadIdx.x;  // 384 threads
    float s = 0.f;
    for (int l = 0; l < Lc; l++) s += hp[((size_t)(b * Lc + l)) * 768 + 384 + c];
    glob[b * 384 + c] = s / (float)Lc;
}

__global__ void globbcast_kernel(float* __restrict__ hp, const float* __restrict__ glob, int Lc) {
    int row = blockIdx.x;  // b*Lc + l
    int b = row / Lc;
    int c = threadIdx.x;   // 384 threads
    hp[(size_t)row * 768 + 384 + c] = glob[b * 384 + c];
}

__global__ __launch_bounds__(256)
void score_kernel(const float* __restrict__ p2, const float* __restrict__ w3,
                  const float* __restrict__ b3, float* __restrict__ score) {
    __shared__ float red[256];
    int row = blockIdx.x;  // b*Lc + l
    int tid = threadIdx.x;
    red[tid] = (tid < 192) ? p2[(size_t)row * 192 + tid] * w3[tid] : 0.f;
    __syncthreads();
    for (int st = 128; st > 0; st >>= 1) {
        if (tid < st) red[tid] += red[tid + st];
        __syncthreads();
    }
    if (tid == 0) {
        float x = red[0] + b3[0];
        score[row] = fminf(x, 0.0f) - log1pf(__expf(-fabsf(x)));
    }
}

// ---------------- top-k selection (set-equivalent to jax.lax.top_k) ----------------
__global__ void topk_kernel(const float* __restrict__ score, int* __restrict__ kidx,
                            int Lc, int k) {
    __shared__ float s[196];
    __shared__ int keep[196];
    int b = blockIdx.x, tid = threadIdx.x;
    for (int i = tid; i < Lc; i += 256) s[i] = score[b * Lc + i];
    __syncthreads();
    for (int i = tid; i < Lc; i += 256) {
        float si = s[i];
        int rank = 0;
        for (int j = 0; j < Lc; j++) {
            float sj = s[j];
            rank += (sj > si) || (sj == si && j < i);
        }
        keep[i] = (rank < k) ? 1 : 0;
    }
    __syncthreads();
    for (int i = tid; i < Lc; i += 256) {
        if (keep[i]) {
            int pos = 0;
            for (int j = 0; j < i; j++) pos += keep[j];
            kidx[b * MAXK + pos] = i;
        }
    }
}

__global__ void gather_kernel(const float* __restrict__ t, const int* __restrict__ kidx,
                              float* __restrict__ dst, int L, int Lnew) {
    int row = blockIdx.x;  // b*Lnew + m
    int b = row / Lnew, m = row % Lnew;
    int srcrow = (m == 0) ? b * L : b * L + 1 + kidx[b * MAXK + m - 1];
    const float* sp = t + (size_t)srcrow * 768;
    float* dp = dst + (size_t)row * 768;
    for (int c = threadIdx.x; c < 768; c += 256) dp[c] = sp[c];
}

// ---------------- host orchestration ----------------
extern "C" void kernel_launch(void* const* d_in, const int* in_sizes, int n_in,
                              void* d_out, int out_size, void* d_ws, size_t ws_size,
                              hipStream_t stream) {
    const float* x        = (const float*)d_in[0];
    const float* patch_w  = (const float*)d_in[1];
    const float* patch_b  = (const float*)d_in[2];
    const float* cls_tok  = (const float*)d_in[3];
    const float* pos_emb  = (const float*)d_in[4];
    const float* ln1_g    = (const float*)d_in[5];
    const float* ln1_b    = (const float*)d_in[6];
    const float* qkv_w    = (const float*)d_in[7];
    const float* qkv_b    = (const float*)d_in[8];
    const float* proj_w   = (const float*)d_in[9];
    const float* proj_b   = (const float*)d_in[10];
    const float* ln2_g    = (const float*)d_in[11];
    const float* ln2_b    = (const float*)d_in[12];
    const float* fc1_w    = (const float*)d_in[13];
    const float* fc1_b    = (const float*)d_in[14];
    const float* fc2_w    = (const float*)d_in[15];
    const float* fc2_b    = (const float*)d_in[16];
    const float* pln_g    = (const float*)d_in[17];
    const float* pln_b    = (const float*)d_in[18];
    const float* pin_w    = (const float*)d_in[19];
    const float* pin_b    = (const float*)d_in[20];
    const float* pw1      = (const float*)d_in[21];
    const float* pb1      = (const float*)d_in[22];
    const float* pw2      = (const float*)d_in[23];
    const float* pb2      = (const float*)d_in[24];
    const float* pw3      = (const float*)d_in[25];
    const float* pb3      = (const float*)d_in[26];
    const float* norm_g   = (const float*)d_in[27];
    const float* norm_b   = (const float*)d_in[28];
    const float* head_w   = (const float*)d_in[29];
    const float* head_b   = (const float*)d_in[30];

    float* ws = (float*)d_ws;
    float* T0    = ws + OFF_T0;
    float* T1    = ws + OFF_T1;
    float* T2    = ws + OFF_T2;
    float* GLOB  = ws + OFF_GLOB;
    float* SCORE = ws + OFF_SCORE;
    int*   KIDX  = (int*)(ws + OFF_KIDX);
    float* CLS   = ws + OFF_CLS;

    // patch embed: rearrange -> GEMM -> assemble (+cls, +pos)
    patch_kernel<<<(BATCH * 196 * 768) / 256, 256, 0, stream>>>(x, T1);
    gemm(stream, T1, patch_w, patch_b, nullptr, T2, BATCH * 196, 768, 768, 0);
    assemble_kernel<<<BATCH * 197, 256, 0, stream>>>(T2, cls_tok, pos_emb, T0);

    int L = 197;
    for (int i = 0; i < DEPTH; i++) {
        if (i == 3 || i == 6 || i == 9) {
            int s = i / 3 - 1;
            int Lc = L - 1;
            int k = (7 * Lc + 9) / 10;  // ceil(0.7*Lc): 196->138, 138->97, 97->68
            // predictor
            ln_kernel<<<BATCH * Lc, 256, 0, stream>>>(T0, T1, pln_g + s * 768, pln_b + s * 768,
                                                      Lc, L, 1, Lc, 0);
            gemm(stream, T1, pin_w + (size_t)s * 768 * 768, pin_b + s * 768, nullptr, T2,
                 BATCH * Lc, 768, 768, 1);
            globmean_kernel<<<BATCH, 384, 0, stream>>>(T2, GLOB, Lc);
            globbcast_kernel<<<BATCH * Lc, 384, 0, stream>>>(T2, GLOB, Lc);
            gemm(stream, T2, pw1 + (size_t)s * 384 * 768, pb1 + s * 384, nullptr, T1,
                 BATCH * Lc, 384, 768, 1);
            float* P2 = T1 + 2500000;
            gemm(stream, T1, pw2 + (size_t)s * 192 * 384, pb2 + s * 192, nullptr, P2,
                 BATCH * Lc, 192, 384, 1);
            score_kernel<<<BATCH * Lc, 256, 0, stream>>>(P2, pw3 + s * 192, pb3 + s, SCORE);
            topk_kernel<<<BATCH, 256, 0, stream>>>(SCORE, KIDX, Lc, k);
            int Lnew = k + 1;
            gather_kernel<<<BATCH * Lnew, 256, 0, stream>>>(T0, KIDX, T1, L, Lnew);
            hipMemcpyAsync(T0, T1, (size_t)BATCH * Lnew * 768 * sizeof(float),
                           hipMemcpyDeviceToDevice, stream);
            L = Lnew;
        }
        int M = BATCH * L;
        // attention sub-block
        ln_kernel<<<M, 256, 0, stream>>>(T0, T1, ln1_g + i * 768, ln1_b + i * 768, L, L, 0, L, 0);
        gemm(stream, T1, qkv_w + (size_t)i * 2304 * 768, qkv_b + i * 2304, nullptr, T2,
             M, 2304, 768, 0);
        attn_kernel<<<BATCH * NHEAD * L, 128, 0, stream>>>(T2, T1, L);
        gemm(stream, T1, proj_w + (size_t)i * 768 * 768, proj_b + i * 768, T0, T0,
             M, 768, 768, 2);
        // MLP sub-block
        ln_kernel<<<M, 256, 0, stream>>>(T0, T1, ln2_g + i * 768, ln2_b + i * 768, L, L, 0, L, 0);
        gemm(stream, T1, fc1_w + (size_t)i * 3072 * 768, fc1_b + i * 3072, nullptr, T2,
             M, 3072, 768, 1);
        gemm(stream, T2, fc2_w + (size_t)i * 768 * 3072, fc2_b + i * 768, T0, T0,
             M, 768, 3072, 2);
    }
    // final LN on cls rows only + head
    ln_kernel<<<BATCH, 256, 0, stream>>>(T0, CLS, norm_g, norm_b, 1, L, 0, 1, 0);
    gemm(stream, CLS, head_w, head_b, nullptr, (float*)d_out, BATCH, 1000, 768, 0);
}

// Round 2
// 14485.587 us; speedup vs baseline: 1.0942x; 1.0942x over previous
//
#include <hip/hip_runtime.h>
#include <hip/hip_bf16.h>
#include <math.h>

// ---------------- model constants ----------------
constexpr int BATCH = 32;
constexpr int DMODEL = 768;
constexpr int NHEAD = 12;
constexpr int DEPTH = 12;
constexpr int L0TOK = 196;
constexpr int MAXK = 138;
constexpr float ATT_SCALE = 0.125f;

// workspace layout (float offsets)
constexpr size_t SZ_T = (size_t)BATCH * 197 * DMODEL;
constexpr size_t SZ_BIG = (size_t)BATCH * 197 * 3072;
constexpr size_t OFF_T0 = 0;
constexpr size_t OFF_T1 = SZ_T;
constexpr size_t OFF_T2 = 2 * SZ_T;
constexpr size_t OFF_GLOB = OFF_T2 + SZ_BIG;
constexpr size_t OFF_SCORE = OFF_GLOB + (size_t)BATCH * 384;
constexpr size_t OFF_KIDX = OFF_SCORE + (size_t)BATCH * L0TOK;
constexpr size_t OFF_CLS = OFF_KIDX + (size_t)BATCH * 140;

__device__ __forceinline__ float gelu_f(float x) {
    return 0.5f * x * (1.0f + erff(x * 0.7071067811865476f));
}
__device__ __forceinline__ float dot4(float4 a, float4 b) {
    return a.x * b.x + a.y * b.y + a.z * b.z + a.w * b.w;
}

// ---------------- patch rearrange ----------------
__global__ void patch_kernel(const float* __restrict__ x, float* __restrict__ p) {
    int idx = blockIdx.x * 256 + threadIdx.x;
    int c = idx % 768;
    int rest = idx / 768;
    int l = rest % 196;
    int b = rest / 196;
    int ch = c >> 8;
    int py = (c & 255) >> 4;
    int px = c & 15;
    int gy = l / 14, gx = l % 14;
    p[idx] = x[(((size_t)b * 3 + ch) * 224 + gy * 16 + py) * 224 + gx * 16 + px];
}

// ---------------- assemble t = [cls; patches] + pos ----------------
__global__ void assemble_kernel(const float* __restrict__ pe, const float* __restrict__ cls,
                                const float* __restrict__ pos, float* __restrict__ t) {
    int row = blockIdx.x;
    int b = row / 197, l = row % 197;
    for (int c = threadIdx.x; c < 768; c += 256) {
        float v = (l == 0) ? cls[c] : pe[((size_t)(b * 196 + l - 1)) * 768 + c];
        t[(size_t)row * 768 + c] = v + pos[l * 768 + c];
    }
}

// ---------------- layernorm ----------------
__global__ __launch_bounds__(256)
void ln_kernel(const float* __restrict__ src, float* __restrict__ dst,
               const float* __restrict__ g, const float* __restrict__ bb,
               int R, int SB, int SO, int DB, int DO_) {
    __shared__ float red[256];
    int row = blockIdx.x;
    int b = row / R, r = row % R;
    const float* sp = src + ((size_t)b * SB + SO + r) * 768;
    float* dp = dst + ((size_t)b * DB + DO_ + r) * 768;
    int tid = threadIdx.x;
    float x0 = sp[tid], x1 = sp[tid + 256], x2 = sp[tid + 512];
    red[tid] = x0 + x1 + x2;
    __syncthreads();
    for (int st = 128; st > 0; st >>= 1) {
        if (tid < st) red[tid] += red[tid + st];
        __syncthreads();
    }
    float mean = red[0] * (1.0f / 768.0f);
    __syncthreads();
    float d0 = x0 - mean, d1 = x1 - mean, d2 = x2 - mean;
    red[tid] = d0 * d0 + d1 * d1 + d2 * d2;
    __syncthreads();
    for (int st = 128; st > 0; st >>= 1) {
        if (tid < st) red[tid] += red[tid + st];
        __syncthreads();
    }
    float inv = rsqrtf(red[0] * (1.0f / 768.0f) + 1e-6f);
    dp[tid]       = d0 * inv * g[tid]       + bb[tid];
    dp[tid + 256] = d1 * inv * g[tid + 256] + bb[tid + 256];
    dp[tid + 512] = d2 * inv * g[tid + 512] + bb[tid + 512];
}

// ---------------- GEMM: C = A(MxK) @ W(NxK)^T + bias [+gelu | +res] ----------------
// 128x64 tile, 256 threads, 8x4 acc/thread. EPI: 0=bias, 1=bias+gelu, 2=bias+res
template <int EPI>
__global__ __launch_bounds__(256)
void gemm_kernel(const float* __restrict__ A, const float* __restrict__ W,
                 const float* __restrict__ bias, const float* __restrict__ res,
                 float* __restrict__ C, int M, int N, int K) {
    __shared__ float As[16][128];
    __shared__ float Ws[16][64];
    int tid = threadIdx.x;
    int tx = tid & 15, ty = tid >> 4;
    int m0 = blockIdx.y * 128, n0 = blockIdx.x * 64;
    int arow = tid >> 1;
    int akh = (tid & 1) * 8;
    int brow = tid & 63;
    int bkq = (tid >> 6) * 4;
    const float* Arow = A + (size_t)(m0 + arow) * K;
    const float* Wrow = W + (size_t)(n0 + brow) * K;
    bool aval = (m0 + arow) < M;
    bool bval = (n0 + brow) < N;
    float acc[8][4] = {};
    for (int kb = 0; kb < K; kb += 16) {
        float4 av0 = make_float4(0.f, 0.f, 0.f, 0.f), av1 = av0, bv0 = av0;
        if (aval) {
            av0 = *(const float4*)(Arow + kb + akh);
            av1 = *(const float4*)(Arow + kb + akh + 4);
        }
        if (bval) bv0 = *(const float4*)(Wrow + kb + bkq);
        __syncthreads();
        As[akh + 0][arow] = av0.x; As[akh + 1][arow] = av0.y;
        As[akh + 2][arow] = av0.z; As[akh + 3][arow] = av0.w;
        As[akh + 4][arow] = av1.x; As[akh + 5][arow] = av1.y;
        As[akh + 6][arow] = av1.z; As[akh + 7][arow] = av1.w;
        Ws[bkq + 0][brow] = bv0.x; Ws[bkq + 1][brow] = bv0.y;
        Ws[bkq + 2][brow] = bv0.z; Ws[bkq + 3][brow] = bv0.w;
        __syncthreads();
#pragma unroll
        for (int kk = 0; kk < 16; kk++) {
            float4 a0 = *(const float4*)&As[kk][ty * 8];
            float4 a1 = *(const float4*)&As[kk][ty * 8 + 4];
            float4 b0 = *(const float4*)&Ws[kk][tx * 4];
            float a[8] = {a0.x, a0.y, a0.z, a0.w, a1.x, a1.y, a1.z, a1.w};
            float bb4[4] = {b0.x, b0.y, b0.z, b0.w};
#pragma unroll
            for (int i = 0; i < 8; i++)
#pragma unroll
                for (int j = 0; j < 4; j++) acc[i][j] += a[i] * bb4[j];
        }
    }
#pragma unroll
    for (int i = 0; i < 8; i++) {
        int m = m0 + ty * 8 + i;
        if (m >= M) break;
        int n = n0 + tx * 4;
        if (n >= N) continue;
        float4 v = make_float4(acc[i][0] + bias[n], acc[i][1] + bias[n + 1],
                               acc[i][2] + bias[n + 2], acc[i][3] + bias[n + 3]);
        if (EPI == 1) {
            v.x = gelu_f(v.x); v.y = gelu_f(v.y); v.z = gelu_f(v.z); v.w = gelu_f(v.w);
        }
        if (EPI == 2) {
            const float4 r = *(const float4*)(res + (size_t)m * N + n);
            v.x += r.x; v.y += r.y; v.z += r.z; v.w += r.w;
        }
        *(float4*)(C + (size_t)m * N + n) = v;
    }
}

static inline void gemm(hipStream_t st, const float* A, const float* W, const float* bias,
                        const float* res, float* C, int M, int N, int K, int epi) {
    dim3 g((N + 63) / 64, (M + 127) / 128), b(256);
    if (epi == 0)      gemm_kernel<0><<<g, b, 0, st>>>(A, W, bias, res, C, M, N, K);
    else if (epi == 1) gemm_kernel<1><<<g, b, 0, st>>>(A, W, bias, res, C, M, N, K);
    else               gemm_kernel<2><<<g, b, 0, st>>>(A, W, bias, res, C, M, N, K);
}

// ---------------- attention v2: block per (b, h, 32-query tile) ----------------
// LDS: Qs 32x68, KVs 64x68 (K then V chunks), Ss 32x204 (full score rows)
__global__ __launch_bounds__(256)
void attn_v2(const float* __restrict__ qkv, float* __restrict__ o, int L, int QT) {
    __shared__ float Qs[32][68];
    __shared__ float KVs[64][68];
    __shared__ float Ss[32][204];
    __shared__ float red8[256];
    __shared__ float rowstat[32];
    int tid = threadIdx.x;
    int idx = blockIdx.x;
    int qt = idx % QT; idx /= QT;
    int h = idx % NHEAD;
    int b = idx / NHEAD;
    int q0 = qt * 32;
    const float* base = qkv + (size_t)b * L * 2304 + h * 64;
    // phase 0: load Q tile
    {
        int row = tid >> 3, dg = (tid & 7) * 8;
        bool v = (q0 + row) < L;
        const float* src = base + (size_t)(q0 + row) * 2304 + dg;
        float4 z = make_float4(0.f, 0.f, 0.f, 0.f);
        *(float4*)&Qs[row][dg]     = v ? *(const float4*)(src)     : z;
        *(float4*)&Qs[row][dg + 4] = v ? *(const float4*)(src + 4) : z;
    }
    int nchunk = (L + 63) >> 6;
    int Lc4 = (L + 3) & ~3;
    // ---- phase 1: scores ----
    {
        int qq = tid & 7;         // q = qq + 8*qi
        int jg = tid >> 3;        // j = jc*64 + jg + 32*ji
        for (int jc = 0; jc < nchunk; jc++) {
            __syncthreads();
            {
                int row = tid >> 2, dg = (tid & 3) * 16;
                int j = jc * 64 + row;
                bool v = j < L;
                const float* src = base + (size_t)j * 2304 + 768 + dg;
                float4 z = make_float4(0.f, 0.f, 0.f, 0.f);
#pragma unroll
                for (int i = 0; i < 4; i++)
                    *(float4*)&KVs[row][dg + 4 * i] = v ? *(const float4*)(src + 4 * i) : z;
            }
            __syncthreads();
            float sacc[4][2] = {};
#pragma unroll 4
            for (int d4 = 0; d4 < 64; d4 += 4) {
                float4 qa[4], ka[2];
#pragma unroll
                for (int qi = 0; qi < 4; qi++) qa[qi] = *(const float4*)&Qs[qq + 8 * qi][d4];
#pragma unroll
                for (int ji = 0; ji < 2; ji++) ka[ji] = *(const float4*)&KVs[jg + 32 * ji][d4];
#pragma unroll
                for (int qi = 0; qi < 4; qi++)
#pragma unroll
                    for (int ji = 0; ji < 2; ji++) sacc[qi][ji] += dot4(qa[qi], ka[ji]);
            }
#pragma unroll
            for (int qi = 0; qi < 4; qi++)
#pragma unroll
                for (int ji = 0; ji < 2; ji++) {
                    int j = jc * 64 + jg + 32 * ji;
                    float sv = (j < L) ? sacc[qi][ji] * ATT_SCALE : 0.f;
                    if (j < Lc4) Ss[qq + 8 * qi][j] = sv;
                }
        }
    }
    __syncthreads();
    // ---- phase 2: softmax over rows ----
    {
        int q = tid & 31, c = tid >> 5;  // c in 0..7
        float mx = -1e30f;
        for (int j = c; j < L; j += 8) mx = fmaxf(mx, Ss[q][j]);
        red8[c * 32 + q] = mx;
        __syncthreads();
        if (tid < 32) {
            float m2 = red8[tid];
#pragma unroll
            for (int cc = 1; cc < 8; cc++) m2 = fmaxf(m2, red8[cc * 32 + tid]);
            rowstat[tid] = m2;
        }
        __syncthreads();
        mx = rowstat[q];
        float sm = 0.f;
        for (int j = c; j < L; j += 8) {
            float e = __expf(Ss[q][j] - mx);
            Ss[q][j] = e;
            sm += e;
        }
        red8[c * 32 + q] = sm;
        __syncthreads();
        if (tid < 32) {
            float s2 = red8[tid];
#pragma unroll
            for (int cc = 1; cc < 8; cc++) s2 += red8[cc * 32 + tid];
            rowstat[tid] = 1.0f / s2;
        }
    }
    // ---- phase 3: O = P @ V ----
    int qq2 = tid & 15, g4 = (tid >> 4) * 4;
    float O[2][4] = {};
    for (int jc = 0; jc < nchunk; jc++) {
        __syncthreads();
        {
            int row = tid >> 2, dg = (tid & 3) * 16;
            int j = jc * 64 + row;
            bool v = j < L;
            const float* src = base + (size_t)j * 2304 + 1536 + dg;
            float4 z = make_float4(0.f, 0.f, 0.f, 0.f);
#pragma unroll
            for (int i = 0; i < 4; i++)
                *(float4*)&KVs[row][dg + 4 * i] = v ? *(const float4*)(src + 4 * i) : z;
        }
        __syncthreads();
        int jmax = min(64, L - jc * 64);
        for (int j4 = 0; j4 < jmax; j4 += 4) {
            float4 p0 = *(const float4*)&Ss[qq2][jc * 64 + j4];
            float4 p1 = *(const float4*)&Ss[qq2 + 16][jc * 64 + j4];
            float pa0[4] = {p0.x, p0.y, p0.z, p0.w};
            float pa1[4] = {p1.x, p1.y, p1.z, p1.w};
#pragma unroll
            for (int jj = 0; jj < 4; jj++) {
                float4 kv = *(const float4*)&KVs[j4 + jj][g4];
                O[0][0] += pa0[jj] * kv.x; O[0][1] += pa0[jj] * kv.y;
                O[0][2] += pa0[jj] * kv.z; O[0][3] += pa0[jj] * kv.w;
                O[1][0] += pa1[jj] * kv.x; O[1][1] += pa1[jj] * kv.y;
                O[1][2] += pa1[jj] * kv.z; O[1][3] += pa1[jj] * kv.w;
            }
        }
    }
#pragma unroll
    for (int qi = 0; qi < 2; qi++) {
        int q = qq2 + 16 * qi;
        if (q0 + q < L) {
            float inv = rowstat[q];
            float4 v = make_float4(O[qi][0] * inv, O[qi][1] * inv,
                                   O[qi][2] * inv, O[qi][3] * inv);
            *(float4*)(o + ((size_t)(b * L + q0 + q)) * 768 + h * 64 + g4) = v;
        }
    }
}

// ---------------- predictor helpers ----------------
__global__ void globmean_kernel(const float* __restrict__ hp, float* __restrict__ glob, int Lc) {
    int b = blockIdx.x;
    int c = threadIdx.x;
    float s = 0.f;
    for (int l = 0; l < Lc; l++) s += hp[((size_t)(b * Lc + l)) * 768 + 384 + c];
    glob[b * 384 + c] = s / (float)Lc;
}

__global__ void globbcast_kernel(float* __restrict__ hp, const float* __restrict__ glob, int Lc) {
    int row = blockIdx.x;
    int b = row / Lc;
    int c = threadIdx.x;
    hp[(size_t)row * 768 + 384 + c] = glob[b * 384 + c];
}

__global__ __launch_bounds__(256)
void score_kernel(const float* __restrict__ p2, const float* __restrict__ w3,
                  const float* __restrict__ b3, float* __restrict__ score) {
    __shared__ float red[256];
    int row = blockIdx.x;
    int tid = threadIdx.x;
    red[tid] = (tid < 192) ? p2[(size_t)row * 192 + tid] * w3[tid] : 0.f;
    __syncthreads();
    for (int st = 128; st > 0; st >>= 1) {
        if (tid < st) red[tid] += red[tid + st];
        __syncthreads();
    }
    if (tid == 0) {
        float x = red[0] + b3[0];
        score[row] = fminf(x, 0.0f) - log1pf(__expf(-fabsf(x)));
    }
}

// ---------------- top-k (set-equivalent to jax.lax.top_k) ----------------
__global__ void topk_kernel(const float* __restrict__ score, int* __restrict__ kidx,
                            int Lc, int k) {
    __shared__ float s[196];
    __shared__ int keep[196];
    int b = blockIdx.x, tid = threadIdx.x;
    for (int i = tid; i < Lc; i += 256) s[i] = score[b * Lc + i];
    __syncthreads();
    for (int i = tid; i < Lc; i += 256) {
        float si = s[i];
        int rank = 0;
        for (int j = 0; j < Lc; j++) {
            float sj = s[j];
            rank += (sj > si) || (sj == si && j < i);
        }
        keep[i] = (rank < k) ? 1 : 0;
    }
    __syncthreads();
    for (int i = tid; i < Lc; i += 256) {
        if (keep[i]) {
            int pos = 0;
            for (int j = 0; j < i; j++) pos += keep[j];
            kidx[b * MAXK + pos] = i;
        }
    }
}

__global__ void gather_kernel(const float* __restrict__ t, const int* __restrict__ kidx,
                              float* __restrict__ dst, int L, int Lnew) {
    int row = blockIdx.x;
    int b = row / Lnew, m = row % Lnew;
    int srcrow = (m == 0) ? b * L : b * L + 1 + kidx[b * MAXK + m - 1];
    const float* sp = t + (size_t)srcrow * 768;
    float* dp = dst + (size_t)row * 768;
    for (int c = threadIdx.x; c < 768; c += 256) dp[c] = sp[c];
}

// ---------------- host orchestration ----------------
extern "C" void kernel_launch(void* const* d_in, const int* in_sizes, int n_in,
                              void* d_out, int out_size, void* d_ws, size_t ws_size,
                              hipStream_t stream) {
    const float* x        = (const float*)d_in[0];
    const float* patch_w  = (const float*)d_in[1];
    const float* patch_b  = (const float*)d_in[2];
    const float* cls_tok  = (const float*)d_in[3];
    const float* pos_emb  = (const float*)d_in[4];
    const float* ln1_g    = (const float*)d_in[5];
    const float* ln1_b    = (const float*)d_in[6];
    const float* qkv_w    = (const float*)d_in[7];
    const float* qkv_b    = (const float*)d_in[8];
    const float* proj_w   = (const float*)d_in[9];
    const float* proj_b   = (const float*)d_in[10];
    const float* ln2_g    = (const float*)d_in[11];
    const float* ln2_b    = (const float*)d_in[12];
    const float* fc1_w    = (const float*)d_in[13];
    const float* fc1_b    = (const float*)d_in[14];
    const float* fc2_w    = (const float*)d_in[15];
    const float* fc2_b    = (const float*)d_in[16];
    const float* pln_g    = (const float*)d_in[17];
    const float* pln_b    = (const float*)d_in[18];
    const float* pin_w    = (const float*)d_in[19];
    const float* pin_b    = (const float*)d_in[20];
    const float* pw1      = (const float*)d_in[21];
    const float* pb1      = (const float*)d_in[22];
    const float* pw2      = (const float*)d_in[23];
    const float* pb2      = (const float*)d_in[24];
    const float* pw3      = (const float*)d_in[25];
    const float* pb3      = (const float*)d_in[26];
    const float* norm_g   = (const float*)d_in[27];
    const float* norm_b   = (const float*)d_in[28];
    const float* head_w   = (const float*)d_in[29];
    const float* head_b   = (const float*)d_in[30];

    float* ws = (float*)d_ws;
    float* cur   = ws + OFF_T0;
    float* tmp   = ws + OFF_T1;
    float* T2    = ws + OFF_T2;
    float* GLOB  = ws + OFF_GLOB;
    float* SCORE = ws + OFF_SCORE;
    int*   KIDX  = (int*)(ws + OFF_KIDX);
    float* CLS   = ws + OFF_CLS;

    // patch embed
    patch_kernel<<<(BATCH * 196 * 768) / 256, 256, 0, stream>>>(x, tmp);
    gemm(stream, tmp, patch_w, patch_b, nullptr, T2, BATCH * 196, 768, 768, 0);
    assemble_kernel<<<BATCH * 197, 256, 0, stream>>>(T2, cls_tok, pos_emb, cur);

    int L = 197;
    for (int i = 0; i < DEPTH; i++) {
        if (i == 3 || i == 6 || i == 9) {
            int s = i / 3 - 1;
            int Lc = L - 1;
            int k = (7 * Lc + 9) / 10;  // ceil(0.7*Lc)
            ln_kernel<<<BATCH * Lc, 256, 0, stream>>>(cur, tmp, pln_g + s * 768, pln_b + s * 768,
                                                      Lc, L, 1, Lc, 0);
            gemm(stream, tmp, pin_w + (size_t)s * 768 * 768, pin_b + s * 768, nullptr, T2,
                 BATCH * Lc, 768, 768, 1);
            globmean_kernel<<<BATCH, 384, 0, stream>>>(T2, GLOB, Lc);
            globbcast_kernel<<<BATCH * Lc, 384, 0, stream>>>(T2, GLOB, Lc);
            gemm(stream, T2, pw1 + (size_t)s * 384 * 768, pb1 + s * 384, nullptr, tmp,
                 BATCH * Lc, 384, 768, 1);
            float* P2 = tmp + 2500000;
            gemm(stream, tmp, pw2 + (size_t)s * 192 * 384, pb2 + s * 192, nullptr, P2,
                 BATCH * Lc, 192, 384, 1);
            score_kernel<<<BATCH * Lc, 256, 0, stream>>>(P2, pw3 + s * 192, pb3 + s, SCORE);
            topk_kernel<<<BATCH, 256, 0, stream>>>(SCORE, KIDX, Lc, k);
            int Lnew = k + 1;
            gather_kernel<<<BATCH * Lnew, 256, 0, stream>>>(cur, KIDX, tmp, L, Lnew);
            float* t_ = cur; cur = tmp; tmp = t_;
            L = Lnew;
        }
        int M = BATCH * L;
        int QT = (L + 31) / 32;
        // attention
        ln_kernel<<<M, 256, 0, stream>>>(cur, tmp, ln1_g + i * 768, ln1_b + i * 768, L, L, 0, L, 0);
        gemm(stream, tmp, qkv_w + (size_t)i * 2304 * 768, qkv_b + i * 2304, nullptr, T2,
             M, 2304, 768, 0);
        attn_v2<<<BATCH * NHEAD * QT, 256, 0, stream>>>(T2, tmp, L, QT);
        gemm(stream, tmp, proj_w + (size_t)i * 768 * 768, proj_b + i * 768, cur, cur,
             M, 768, 768, 2);
        // MLP
        ln_kernel<<<M, 256, 0, stream>>>(cur, tmp, ln2_g + i * 768, ln2_b + i * 768, L, L, 0, L, 0);
        gemm(stream, tmp, fc1_w + (size_t)i * 3072 * 768, fc1_b + i * 3072, nullptr, T2,
             M, 3072, 768, 1);
        gemm(stream, T2, fc2_w + (size_t)i * 768 * 3072, fc2_b + i * 768, cur, cur,
             M, 768, 3072, 2);
    }
    ln_kernel<<<BATCH, 256, 0, stream>>>(cur, CLS, norm_g, norm_b, 1, L, 0, 1, 0);
    gemm(stream, CLS, head_w, head_b, nullptr, (float*)d_out, BATCH, 1000, 768, 0);
}

// Round 3
// 4389.919 us; speedup vs baseline: 3.6107x; 3.2997x over previous
//
#include <hip/hip_runtime.h>
#include <hip/hip_bf16.h>
#include <math.h>

// ---------------- model constants ----------------
constexpr int BATCH = 32;
constexpr int NHEAD = 12;
constexpr int DEPTH = 12;
constexpr int L0TOK = 196;
constexpr int MAXK = 138;
constexpr float ATT_SCALE = 0.125f;

// workspace layout (float-slot offsets)
constexpr size_t SZ_T = (size_t)BATCH * 197 * 768;            // 4,841,472
constexpr size_t OFF_T0 = 0;
constexpr size_t OFF_T1 = SZ_T;
constexpr size_t OFF_C32 = 2 * SZ_T;                          // 14,524,416 floats (qkv out / fc1-out bf16 / pred out)
constexpr size_t OFF_ABF = OFF_C32 + (size_t)BATCH * 197 * 2304;   // bf16 activations (2,420,736 slots)
constexpr size_t OFF_WL  = OFF_ABF + 2420736;                 // bf16 weights (1,179,648 slots = 2.36M elems)
constexpr size_t OFF_GLOB  = OFF_WL + 1179648;
constexpr size_t OFF_SCORE = OFF_GLOB + (size_t)BATCH * 384;
constexpr size_t OFF_KIDX  = OFF_SCORE + (size_t)BATCH * L0TOK;
constexpr size_t OFF_CLS   = OFF_KIDX + (size_t)BATCH * 140;

typedef __attribute__((ext_vector_type(8))) short short8;
typedef __attribute__((ext_vector_type(4))) float float4v;

__device__ __forceinline__ float gelu_f(float x) {
    return 0.5f * x * (1.0f + erff(x * 0.7071067811865476f));
}
__device__ __forceinline__ float dot4(float4 a, float4 b) {
    return a.x * b.x + a.y * b.y + a.z * b.z + a.w * b.w;
}

// async 16B global->LDS (DMA, no VGPR round trip)
__device__ __forceinline__ void load_lds16(const void* g, void* l) {
    __builtin_amdgcn_global_load_lds(
        (const __attribute__((address_space(1))) unsigned int*)g,
        (__attribute__((address_space(3))) unsigned int*)l, 16, 0, 0);
}

// ---------------- fp32 -> bf16 weight conversion ----------------
__global__ void cvt_kernel(const float* __restrict__ src, __hip_bfloat16* __restrict__ dst, int n) {
    int i = (blockIdx.x * 256 + threadIdx.x) * 4;
    if (i >= n) return;
    float4 v = *(const float4*)(src + i);
    dst[i + 0] = __float2bfloat16(v.x);
    dst[i + 1] = __float2bfloat16(v.y);
    dst[i + 2] = __float2bfloat16(v.z);
    dst[i + 3] = __float2bfloat16(v.w);
}
static inline void cvt(hipStream_t st, const float* s, __hip_bfloat16* d, size_t n) {
    cvt_kernel<<<(n / 4 + 255) / 256, 256, 0, st>>>(s, d, (int)n);
}

// ---------------- patch rearrange (bf16 out) ----------------
__global__ void patch_kernel(const float* __restrict__ x, __hip_bfloat16* __restrict__ p) {
    int idx = blockIdx.x * 256 + threadIdx.x;
    int c = idx % 768;
    int rest = idx / 768;
    int l = rest % 196;
    int b = rest / 196;
    int ch = c >> 8;
    int py = (c & 255) >> 4;
    int px = c & 15;
    int gy = l / 14, gx = l % 14;
    p[idx] = __float2bfloat16(
        x[(((size_t)b * 3 + ch) * 224 + gy * 16 + py) * 224 + gx * 16 + px]);
}

// ---------------- assemble t = [cls; patches] + pos (fp32) ----------------
__global__ void assemble_kernel(const float* __restrict__ pe, const float* __restrict__ cls,
                                const float* __restrict__ pos, float* __restrict__ t) {
    int row = blockIdx.x;
    int b = row / 197, l = row % 197;
    for (int c = threadIdx.x; c < 768; c += 256) {
        float v = (l == 0) ? cls[c] : pe[((size_t)(b * 196 + l - 1)) * 768 + c];
        t[(size_t)row * 768 + c] = v + pos[l * 768 + c];
    }
}

// ---------------- layernorm, templated output type ----------------
template <typename OT>
__global__ __launch_bounds__(256)
void ln_kernel(const float* __restrict__ src, OT* __restrict__ dst,
               const float* __restrict__ g, const float* __restrict__ bb,
               int R, int SB, int SO, int DB, int DO_) {
    __shared__ float red[256];
    int row = blockIdx.x;
    int b = row / R, r = row % R;
    const float* sp = src + ((size_t)b * SB + SO + r) * 768;
    OT* dp = dst + ((size_t)b * DB + DO_ + r) * 768;
    int tid = threadIdx.x;
    float x0 = sp[tid], x1 = sp[tid + 256], x2 = sp[tid + 512];
    red[tid] = x0 + x1 + x2;
    __syncthreads();
    for (int st = 128; st > 0; st >>= 1) {
        if (tid < st) red[tid] += red[tid + st];
        __syncthreads();
    }
    float mean = red[0] * (1.0f / 768.0f);
    __syncthreads();
    float d0 = x0 - mean, d1 = x1 - mean, d2 = x2 - mean;
    red[tid] = d0 * d0 + d1 * d1 + d2 * d2;
    __syncthreads();
    for (int st = 128; st > 0; st >>= 1) {
        if (tid < st) red[tid] += red[tid + st];
        __syncthreads();
    }
    float inv = rsqrtf(red[0] * (1.0f / 768.0f) + 1e-6f);
    dp[tid]       = (OT)(d0 * inv * g[tid]       + bb[tid]);
    dp[tid + 256] = (OT)(d1 * inv * g[tid + 256] + bb[tid + 256]);
    dp[tid + 512] = (OT)(d2 * inv * g[tid + 512] + bb[tid + 512]);
}

// ---------------- MFMA GEMM: C = A(MxK,bf16) @ W(NxK,bf16)^T + bias ----------------
// 128x128 tile, 256 thr (4 waves, 2x2 of 64x64), K-step 32, m97 structure.
// EPI: 0=bias, 1=bias+gelu, 2=bias+residual.  N must be a multiple of 128; K of 32.
template <int EPI, typename CT>
__global__ __launch_bounds__(256)
void gemm_mfma(const __hip_bfloat16* __restrict__ A, const __hip_bfloat16* __restrict__ W,
               const float* __restrict__ bias, const float* __restrict__ res,
               CT* __restrict__ C, int M, int N, int K) {
    __shared__ __hip_bfloat16 As[128 * 32];
    __shared__ __hip_bfloat16 Bs[128 * 32];
    int tid = threadIdx.x;
    int lane = tid & 63;
    int wave = tid >> 6;
    int m0 = blockIdx.y * 128, n0 = blockIdx.x * 128;
    int wm = (wave >> 1) * 64, wn = (wave & 1) * 64;

    // staging chunks: chunk c covers LDS bytes [c*16, c*16+16) == row c>>2, k ((c&3)*8..+8)
    int c0 = tid, c1 = tid + 256;
    int ra0 = c0 >> 2, ka0 = (c0 & 3) << 3;
    int ra1 = c1 >> 2, ka1 = (c1 & 3) << 3;
    const __hip_bfloat16* pa0 = A + (size_t)(m0 + ra0) * K + ka0;
    const __hip_bfloat16* pa1 = A + (size_t)(m0 + ra1) * K + ka1;
    const __hip_bfloat16* pb0 = W + (size_t)(n0 + ra0) * K + ka0;
    const __hip_bfloat16* pb1 = W + (size_t)(n0 + ra1) * K + ka1;
    __hip_bfloat16* la0 = &As[c0 * 8];
    __hip_bfloat16* la1 = &As[c1 * 8];
    __hip_bfloat16* lb0 = &Bs[c0 * 8];
    __hip_bfloat16* lb1 = &Bs[c1 * 8];
    bool va0 = (m0 + ra0) < M, va1 = (m0 + ra1) < M;

    const short* Asp = (const short*)As + (wm + (lane & 15)) * 32 + (lane >> 4) * 8;
    const short* Bsp = (const short*)Bs + (wn + (lane & 15)) * 32 + (lane >> 4) * 8;

    float4v acc[4][4] = {};
    for (int kb = 0; kb < K; kb += 32) {
        if (va0) load_lds16(pa0, la0);
        if (va1) load_lds16(pa1, la1);
        load_lds16(pb0, lb0);
        load_lds16(pb1, lb1);
        pa0 += 32; pa1 += 32; pb0 += 32; pb1 += 32;
        __syncthreads();
        short8 a[4], b[4];
#pragma unroll
        for (int i = 0; i < 4; i++) a[i] = *(const short8*)(Asp + i * 512);
#pragma unroll
        for (int j = 0; j < 4; j++) b[j] = *(const short8*)(Bsp + j * 512);
#pragma unroll
        for (int i = 0; i < 4; i++)
#pragma unroll
            for (int j = 0; j < 4; j++)
                acc[i][j] = __builtin_amdgcn_mfma_f32_16x16x32_bf16(a[i], b[j], acc[i][j], 0, 0, 0);
        __syncthreads();
    }
    // epilogue: row = m0+wm+i*16+(lane>>4)*4+r ; col = n0+wn+j*16+(lane&15)
    int rbase = m0 + wm + (lane >> 4) * 4;
    int cbase = n0 + wn + (lane & 15);
    float bi[4];
#pragma unroll
    for (int j = 0; j < 4; j++) bi[j] = bias[cbase + j * 16];
#pragma unroll
    for (int i = 0; i < 4; i++) {
#pragma unroll
        for (int r = 0; r < 4; r++) {
            int row = rbase + i * 16 + r;
            if (row >= M) continue;
#pragma unroll
            for (int j = 0; j < 4; j++) {
                int col = cbase + j * 16;
                float v = acc[i][j][r] + bi[j];
                if (EPI == 1) v = gelu_f(v);
                if (EPI == 2) v += res[(size_t)row * N + col];
                C[(size_t)row * N + col] = (CT)v;
            }
        }
    }
}

template <typename CT>
static inline void gemm_bf(hipStream_t st, const __hip_bfloat16* A, const __hip_bfloat16* W,
                           const float* bias, const float* res, CT* C,
                           int M, int N, int K, int epi) {
    dim3 g(N / 128, (M + 127) / 128), b(256);
    if (epi == 0)      gemm_mfma<0, CT><<<g, b, 0, st>>>(A, W, bias, res, C, M, N, K);
    else if (epi == 1) gemm_mfma<1, CT><<<g, b, 0, st>>>(A, W, bias, res, C, M, N, K);
    else               gemm_mfma<2, CT><<<g, b, 0, st>>>(A, W, bias, res, C, M, N, K);
}

// ---------------- fp32 GEMM (small predictor/head mats) ----------------
template <int EPI>
__global__ __launch_bounds__(256)
void gemm_kernel(const float* __restrict__ A, const float* __restrict__ W,
                 const float* __restrict__ bias, const float* __restrict__ res,
                 float* __restrict__ C, int M, int N, int K) {
    __shared__ float As[16][128];
    __shared__ float Ws[16][64];
    int tid = threadIdx.x;
    int tx = tid & 15, ty = tid >> 4;
    int m0 = blockIdx.y * 128, n0 = blockIdx.x * 64;
    int arow = tid >> 1;
    int akh = (tid & 1) * 8;
    int brow = tid & 63;
    int bkq = (tid >> 6) * 4;
    const float* Arow = A + (size_t)(m0 + arow) * K;
    const float* Wrow = W + (size_t)(n0 + brow) * K;
    bool aval = (m0 + arow) < M;
    bool bval = (n0 + brow) < N;
    float acc[8][4] = {};
    for (int kb = 0; kb < K; kb += 16) {
        float4 av0 = make_float4(0.f, 0.f, 0.f, 0.f), av1 = av0, bv0 = av0;
        if (aval) {
            av0 = *(const float4*)(Arow + kb + akh);
            av1 = *(const float4*)(Arow + kb + akh + 4);
        }
        if (bval) bv0 = *(const float4*)(Wrow + kb + bkq);
        __syncthreads();
        As[akh + 0][arow] = av0.x; As[akh + 1][arow] = av0.y;
        As[akh + 2][arow] = av0.z; As[akh + 3][arow] = av0.w;
        As[akh + 4][arow] = av1.x; As[akh + 5][arow] = av1.y;
        As[akh + 6][arow] = av1.z; As[akh + 7][arow] = av1.w;
        Ws[bkq + 0][brow] = bv0.x; Ws[bkq + 1][brow] = bv0.y;
        Ws[bkq + 2][brow] = bv0.z; Ws[bkq + 3][brow] = bv0.w;
        __syncthreads();
#pragma unroll
        for (int kk = 0; kk < 16; kk++) {
            float4 a0 = *(const float4*)&As[kk][ty * 8];
            float4 a1 = *(const float4*)&As[kk][ty * 8 + 4];
            float4 b0 = *(const float4*)&Ws[kk][tx * 4];
            float a[8] = {a0.x, a0.y, a0.z, a0.w, a1.x, a1.y, a1.z, a1.w};
            float bb4[4] = {b0.x, b0.y, b0.z, b0.w};
#pragma unroll
            for (int i = 0; i < 8; i++)
#pragma unroll
                for (int j = 0; j < 4; j++) acc[i][j] += a[i] * bb4[j];
        }
    }
#pragma unroll
    for (int i = 0; i < 8; i++) {
        int m = m0 + ty * 8 + i;
        if (m >= M) break;
        int n = n0 + tx * 4;
        if (n >= N) continue;
        float4 v = make_float4(acc[i][0] + bias[n], acc[i][1] + bias[n + 1],
                               acc[i][2] + bias[n + 2], acc[i][3] + bias[n + 3]);
        if (EPI == 1) {
            v.x = gelu_f(v.x); v.y = gelu_f(v.y); v.z = gelu_f(v.z); v.w = gelu_f(v.w);
        }
        if (EPI == 2) {
            const float4 r = *(const float4*)(res + (size_t)m * N + n);
            v.x += r.x; v.y += r.y; v.z += r.z; v.w += r.w;
        }
        *(float4*)(C + (size_t)m * N + n) = v;
    }
}

static inline void gemm(hipStream_t st, const float* A, const float* W, const float* bias,
                        const float* res, float* C, int M, int N, int K, int epi) {
    dim3 g((N + 63) / 64, (M + 127) / 128), b(256);
    if (epi == 0)      gemm_kernel<0><<<g, b, 0, st>>>(A, W, bias, res, C, M, N, K);
    else if (epi == 1) gemm_kernel<1><<<g, b, 0, st>>>(A, W, bias, res, C, M, N, K);
    else               gemm_kernel<2><<<g, b, 0, st>>>(A, W, bias, res, C, M, N, K);
}

// ---------------- attention: block per (b,h,32-query tile), bf16 out ----------------
__global__ __launch_bounds__(256)
void attn_v2(const float* __restrict__ qkv, __hip_bfloat16* __restrict__ o, int L, int QT) {
    __shared__ float Qs[32][68];
    __shared__ float KVs[64][68];
    __shared__ float Ss[32][204];
    __shared__ float red8[256];
    __shared__ float rowstat[32];
    int tid = threadIdx.x;
    int idx = blockIdx.x;
    int qt = idx % QT; idx /= QT;
    int h = idx % NHEAD;
    int b = idx / NHEAD;
    int q0 = qt * 32;
    const float* base = qkv + (size_t)b * L * 2304 + h * 64;
    {
        int row = tid >> 3, dg = (tid & 7) * 8;
        bool v = (q0 + row) < L;
        const float* src = base + (size_t)(q0 + row) * 2304 + dg;
        float4 z = make_float4(0.f, 0.f, 0.f, 0.f);
        *(float4*)&Qs[row][dg]     = v ? *(const float4*)(src)     : z;
        *(float4*)&Qs[row][dg + 4] = v ? *(const float4*)(src + 4) : z;
    }
    int nchunk = (L + 63) >> 6;
    int Lc4 = (L + 3) & ~3;
    {
        int qq = tid & 7;
        int jg = tid >> 3;
        for (int jc = 0; jc < nchunk; jc++) {
            __syncthreads();
            {
                int row = tid >> 2, dg = (tid & 3) * 16;
                int j = jc * 64 + row;
                bool v = j < L;
                const float* src = base + (size_t)j * 2304 + 768 + dg;
                float4 z = make_float4(0.f, 0.f, 0.f, 0.f);
#pragma unroll
                for (int i = 0; i < 4; i++)
                    *(float4*)&KVs[row][dg + 4 * i] = v ? *(const float4*)(src + 4 * i) : z;
            }
            __syncthreads();
            float sacc[4][2] = {};
#pragma unroll 4
            for (int d4 = 0; d4 < 64; d4 += 4) {
                float4 qa[4], ka[2];
#pragma unroll
                for (int qi = 0; qi < 4; qi++) qa[qi] = *(const float4*)&Qs[qq + 8 * qi][d4];
#pragma unroll
                for (int ji = 0; ji < 2; ji++) ka[ji] = *(const float4*)&KVs[jg + 32 * ji][d4];
#pragma unroll
                for (int qi = 0; qi < 4; qi++)
#pragma unroll
                    for (int ji = 0; ji < 2; ji++) sacc[qi][ji] += dot4(qa[qi], ka[ji]);
            }
#pragma unroll
            for (int qi = 0; qi < 4; qi++)
#pragma unroll
                for (int ji = 0; ji < 2; ji++) {
                    int j = jc * 64 + jg + 32 * ji;
                    float sv = (j < L) ? sacc[qi][ji] * ATT_SCALE : 0.f;
                    if (j < Lc4) Ss[qq + 8 * qi][j] = sv;
                }
        }
    }
    __syncthreads();
    {
        int q = tid & 31, c = tid >> 5;
        float mx = -1e30f;
        for (int j = c; j < L; j += 8) mx = fmaxf(mx, Ss[q][j]);
        red8[c * 32 + q] = mx;
        __syncthreads();
        if (tid < 32) {
            float m2 = red8[tid];
#pragma unroll
            for (int cc = 1; cc < 8; cc++) m2 = fmaxf(m2, red8[cc * 32 + tid]);
            rowstat[tid] = m2;
        }
        __syncthreads();
        mx = rowstat[q];
        float sm = 0.f;
        for (int j = c; j < L; j += 8) {
            float e = __expf(Ss[q][j] - mx);
            Ss[q][j] = e;
            sm += e;
        }
        red8[c * 32 + q] = sm;
        __syncthreads();
        if (tid < 32) {
            float s2 = red8[tid];
#pragma unroll
            for (int cc = 1; cc < 8; cc++) s2 += red8[cc * 32 + tid];
            rowstat[tid] = 1.0f / s2;
        }
    }
    int qq2 = tid & 15, g4 = (tid >> 4) * 4;
    float O[2][4] = {};
    for (int jc = 0; jc < nchunk; jc++) {
        __syncthreads();
        {
            int row = tid >> 2, dg = (tid & 3) * 16;
            int j = jc * 64 + row;
            bool v = j < L;
            const float* src = base + (size_t)j * 2304 + 1536 + dg;
            float4 z = make_float4(0.f, 0.f, 0.f, 0.f);
#pragma unroll
            for (int i = 0; i < 4; i++)
                *(float4*)&KVs[row][dg + 4 * i] = v ? *(const float4*)(src + 4 * i) : z;
        }
        __syncthreads();
        int jmax = min(64, L - jc * 64);
        for (int j4 = 0; j4 < jmax; j4 += 4) {
            float4 p0 = *(const float4*)&Ss[qq2][jc * 64 + j4];
            float4 p1 = *(const float4*)&Ss[qq2 + 16][jc * 64 + j4];
            float pa0[4] = {p0.x, p0.y, p0.z, p0.w};
            float pa1[4] = {p1.x, p1.y, p1.z, p1.w};
#pragma unroll
            for (int jj = 0; jj < 4; jj++) {
                float4 kv = *(const float4*)&KVs[j4 + jj][g4];
                O[0][0] += pa0[jj] * kv.x; O[0][1] += pa0[jj] * kv.y;
                O[0][2] += pa0[jj] * kv.z; O[0][3] += pa0[jj] * kv.w;
                O[1][0] += pa1[jj] * kv.x; O[1][1] += pa1[jj] * kv.y;
                O[1][2] += pa1[jj] * kv.z; O[1][3] += pa1[jj] * kv.w;
            }
        }
    }
#pragma unroll
    for (int qi = 0; qi < 2; qi++) {
        int q = qq2 + 16 * qi;
        if (q0 + q < L) {
            float inv = rowstat[q];
            __hip_bfloat16* op = o + ((size_t)(b * L + q0 + q)) * 768 + h * 64 + g4;
            op[0] = __float2bfloat16(O[qi][0] * inv);
            op[1] = __float2bfloat16(O[qi][1] * inv);
            op[2] = __float2bfloat16(O[qi][2] * inv);
            op[3] = __float2bfloat16(O[qi][3] * inv);
        }
    }
}

// ---------------- predictor helpers ----------------
__global__ void globmean_kernel(const float* __restrict__ hp, float* __restrict__ glob, int Lc) {
    int b = blockIdx.x;
    int c = threadIdx.x;
    float s = 0.f;
    for (int l = 0; l < Lc; l++) s += hp[((size_t)(b * Lc + l)) * 768 + 384 + c];
    glob[b * 384 + c] = s / (float)Lc;
}

__global__ void globbcast_kernel(float* __restrict__ hp, const float* __restrict__ glob, int Lc) {
    int row = blockIdx.x;
    int b = row / Lc;
    int c = threadIdx.x;
    hp[(size_t)row * 768 + 384 + c] = glob[b * 384 + c];
}

__global__ __launch_bounds__(256)
void score_kernel(const float* __restrict__ p2, const float* __restrict__ w3,
                  const float* __restrict__ b3, float* __restrict__ score) {
    __shared__ float red[256];
    int row = blockIdx.x;
    int tid = threadIdx.x;
    red[tid] = (tid < 192) ? p2[(size_t)row * 192 + tid] * w3[tid] : 0.f;
    __syncthreads();
    for (int st = 128; st > 0; st >>= 1) {
        if (tid < st) red[tid] += red[tid + st];
        __syncthreads();
    }
    if (tid == 0) {
        float x = red[0] + b3[0];
        score[row] = fminf(x, 0.0f) - log1pf(__expf(-fabsf(x)));
    }
}

// ---------------- top-k (set-equivalent to jax.lax.top_k) ----------------
__global__ void topk_kernel(const float* __restrict__ score, int* __restrict__ kidx,
                            int Lc, int k) {
    __shared__ float s[196];
    __shared__ int keep[196];
    int b = blockIdx.x, tid = threadIdx.x;
    for (int i = tid; i < Lc; i += 256) s[i] = score[b * Lc + i];
    __syncthreads();
    for (int i = tid; i < Lc; i += 256) {
        float si = s[i];
        int rank = 0;
        for (int j = 0; j < Lc; j++) {
            float sj = s[j];
            rank += (sj > si) || (sj == si && j < i);
        }
        keep[i] = (rank < k) ? 1 : 0;
    }
    __syncthreads();
    for (int i = tid; i < Lc; i += 256) {
        if (keep[i]) {
            int pos = 0;
            for (int j = 0; j < i; j++) pos += keep[j];
            kidx[b * MAXK + pos] = i;
        }
    }
}

__global__ void gather_kernel(const float* __restrict__ t, const int* __restrict__ kidx,
                              float* __restrict__ dst, int L, int Lnew) {
    int row = blockIdx.x;
    int b = row / Lnew, m = row % Lnew;
    int srcrow = (m == 0) ? b * L : b * L + 1 + kidx[b * MAXK + m - 1];
    const float* sp = t + (size_t)srcrow * 768;
    float* dp = dst + (size_t)row * 768;
    for (int c = threadIdx.x; c < 768; c += 256) dp[c] = sp[c];
}

// ---------------- host orchestration ----------------
extern "C" void kernel_launch(void* const* d_in, const int* in_sizes, int n_in,
                              void* d_out, int out_size, void* d_ws, size_t ws_size,
                              hipStream_t stream) {
    const float* x        = (const float*)d_in[0];
    const float* patch_w  = (const float*)d_in[1];
    const float* patch_b  = (const float*)d_in[2];
    const float* cls_tok  = (const float*)d_in[3];
    const float* pos_emb  = (const float*)d_in[4];
    const float* ln1_g    = (const float*)d_in[5];
    const float* ln1_b    = (const float*)d_in[6];
    const float* qkv_w    = (const float*)d_in[7];
    const float* qkv_b    = (const float*)d_in[8];
    const float* proj_w   = (const float*)d_in[9];
    const float* proj_b   = (const float*)d_in[10];
    const float* ln2_g    = (const float*)d_in[11];
    const float* ln2_b    = (const float*)d_in[12];
    const float* fc1_w    = (const float*)d_in[13];
    const float* fc1_b    = (const float*)d_in[14];
    const float* fc2_w    = (const float*)d_in[15];
    const float* fc2_b    = (const float*)d_in[16];
    const float* pln_g    = (const float*)d_in[17];
    const float* pln_b    = (const float*)d_in[18];
    const float* pin_w    = (const float*)d_in[19];
    const float* pin_b    = (const float*)d_in[20];
    const float* pw1      = (const float*)d_in[21];
    const float* pb1      = (const float*)d_in[22];
    const float* pw2      = (const float*)d_in[23];
    const float* pb2      = (const float*)d_in[24];
    const float* pw3      = (const float*)d_in[25];
    const float* pb3      = (const float*)d_in[26];
    const float* norm_g   = (const float*)d_in[27];
    const float* norm_b   = (const float*)d_in[28];
    const float* head_w   = (const float*)d_in[29];
    const float* head_b   = (const float*)d_in[30];

    float* ws = (float*)d_ws;
    float* cur   = ws + OFF_T0;
    float* tmp   = ws + OFF_T1;
    float* C32   = ws + OFF_C32;
    __hip_bfloat16* ABF = (__hip_bfloat16*)(ws + OFF_ABF);
    __hip_bfloat16* WL  = (__hip_bfloat16*)(ws + OFF_WL);
    __hip_bfloat16* BBF = (__hip_bfloat16*)C32;  // fc1-out overlays C32 region
    float* GLOB  = ws + OFF_GLOB;
    float* SCORE = ws + OFF_SCORE;
    int*   KIDX  = (int*)(ws + OFF_KIDX);
    float* CLS   = ws + OFF_CLS;

    // patch embed
    cvt(stream, patch_w, WL, 768 * 768);
    patch_kernel<<<(BATCH * 196 * 768) / 256, 256, 0, stream>>>(x, ABF);
    gemm_bf<float>(stream, ABF, WL, patch_b, nullptr, C32, BATCH * 196, 768, 768, 0);
    assemble_kernel<<<BATCH * 197, 256, 0, stream>>>(C32, cls_tok, pos_emb, cur);

    int L = 197;
    for (int i = 0; i < DEPTH; i++) {
        if (i == 3 || i == 6 || i == 9) {
            int s = i / 3 - 1;
            int Lc = L - 1;
            int k = (7 * Lc + 9) / 10;  // ceil(0.7*Lc)
            ln_kernel<__hip_bfloat16><<<BATCH * Lc, 256, 0, stream>>>(
                cur, ABF, pln_g + s * 768, pln_b + s * 768, Lc, L, 1, Lc, 0);
            cvt(stream, pin_w + (size_t)s * 768 * 768, WL, 768 * 768);
            gemm_bf<float>(stream, ABF, WL, pin_b + s * 768, nullptr, C32,
                           BATCH * Lc, 768, 768, 1);
            globmean_kernel<<<BATCH, 384, 0, stream>>>(C32, GLOB, Lc);
            globbcast_kernel<<<BATCH * Lc, 384, 0, stream>>>(C32, GLOB, Lc);
            gemm(stream, C32, pw1 + (size_t)s * 384 * 768, pb1 + s * 384, nullptr, tmp,
                 BATCH * Lc, 384, 768, 1);
            float* P2 = tmp + 2500000;
            gemm(stream, tmp, pw2 + (size_t)s * 192 * 384, pb2 + s * 192, nullptr, P2,
                 BATCH * Lc, 192, 384, 1);
            score_kernel<<<BATCH * Lc, 256, 0, stream>>>(P2, pw3 + s * 192, pb3 + s, SCORE);
            topk_kernel<<<BATCH, 256, 0, stream>>>(SCORE, KIDX, Lc, k);
            int Lnew = k + 1;
            gather_kernel<<<BATCH * Lnew, 256, 0, stream>>>(cur, KIDX, tmp, L, Lnew);
            float* t_ = cur; cur = tmp; tmp = t_;
            L = Lnew;
        }
        int M = BATCH * L;
        int QT = (L + 31) / 32;
        // attention
        ln_kernel<__hip_bfloat16><<<M, 256, 0, stream>>>(
            cur, ABF, ln1_g + i * 768, ln1_b + i * 768, L, L, 0, L, 0);
        cvt(stream, qkv_w + (size_t)i * 2304 * 768, WL, 2304 * 768);
        gemm_bf<float>(stream, ABF, WL, qkv_b + i * 2304, nullptr, C32, M, 2304, 768, 0);
        attn_v2<<<BATCH * NHEAD * QT, 256, 0, stream>>>(C32, ABF, L, QT);
        cvt(stream, proj_w + (size_t)i * 768 * 768, WL, 768 * 768);
        gemm_bf<float>(stream, ABF, WL, proj_b + i * 768, cur, cur, M, 768, 768, 2);
        // MLP
        ln_kernel<__hip_bfloat16><<<M, 256, 0, stream>>>(
            cur, ABF, ln2_g + i * 768, ln2_b + i * 768, L, L, 0, L, 0);
        cvt(stream, fc1_w + (size_t)i * 3072 * 768, WL, 3072 * 768);
        gemm_bf<__hip_bfloat16>(stream, ABF, WL, fc1_b + i * 3072, nullptr, BBF,
                                M, 3072, 768, 1);
        cvt(stream, fc2_w + (size_t)i * 768 * 3072, WL, 768 * 3072);
        gemm_bf<float>(stream, BBF, WL, fc2_b + i * 768, cur, cur, M, 768, 3072, 2);
    }
    ln_kernel<float><<<BATCH, 256, 0, stream>>>(cur, CLS, norm_g, norm_b, 1, L, 0, 1, 0);
    gemm(stream, CLS, head_w, head_b, nullptr, (float*)d_out, BATCH, 1000, 768, 0);
}